// Round 8
// baseline (134.673 us; speedup 1.0000x reference)
//
#include <hip/hip_runtime.h>

static constexpr int OHW = 12, NSP = 144;

// ---------------------------------------------------------------------------
// build_T: gather x (4,256,14,14) -> T[n][k][i], n = b*144+oh*12+ow,
// k = (kh*3+kw)*32 + ic, i in [0,8). One float4 (4 consecutive i) per thread.
// (~4 us; fusing into caps_main regressed in R1.)
// ---------------------------------------------------------------------------
__global__ void build_T(const float* __restrict__ x, float4* __restrict__ T4) {
    const int g = blockIdx.x * 256 + threadIdx.x;   // [0, 576*576)
    const int n = g / 576;                          // 576 float4 per n
    const int q = g - n * 576;
    const int r = q << 2;                           // float offset in row
    const int k = r >> 3;
    const int i0 = r & 7;                           // 0 or 4
    const int ic = k & 31;
    const int kk = k >> 5;
    const int kh = kk / 3, kw = kk - kh * 3;
    const int b = n / NSP;
    const int rm = n - b * NSP;
    const int oh = rm / OHW, ow = rm - oh * OHW;
    const float* xp = x + (size_t)(b * 256 + ic * 8 + i0) * 196
                        + (oh + kh) * 14 + (ow + kw);
    float4 v;
    v.x = xp[0];
    v.y = xp[196];
    v.z = xp[392];
    v.w = xp[588];
    T4[g] = v;
}

__device__ __forceinline__ void fma4(float4& a, float s, const float4& w) {
    a.x = fmaf(s, w.x, a.x);
    a.y = fmaf(s, w.y, a.y);
    a.z = fmaf(s, w.z, a.z);
    a.w = fmaf(s, w.w, a.w);
}

__device__ __forceinline__ void add4(float4& a, const float4& b) {
    a.x += b.x; a.y += b.y; a.z += b.z; a.w += b.w;
}

__device__ __forceinline__ float dot4(const float4& a, const float4& b) {
    return a.x * b.x + a.y * b.y + a.z * b.z + a.w * b.w;
}

// ---- VALU-pipe reduce helpers (R7: ds_bpermute -> DPP, +4 us win) ---------
template <int CTRL>
__device__ __forceinline__ float dppmov(float v) {
    return __int_as_float(__builtin_amdgcn_update_dpp(
        0, __float_as_int(v), CTRL, 0xF, 0xF, true));
}

__device__ __forceinline__ float cred(float v) {       // sum over c-quad
    v += dppmov<0xB1>(v);   // quad_perm [1,0,3,2]
    v += dppmov<0x4E>(v);   // quad_perm [2,3,0,1]
    return v;
}

__device__ __forceinline__ float kred(float v) {       // sum over 16 kgp
    v += dppmov<0x124>(v);  // row_ror:4
    v += dppmov<0x128>(v);  // row_ror:8
    v += __int_as_float(__builtin_amdgcn_ds_swizzle(__float_as_int(v), 0x401F));
    v += __shfl_xor(v, 32);
    return v;
}

__device__ __forceinline__ void kred4(float4& v) {
    v.x = kred(v.x); v.y = kred(v.y); v.z = kred(v.z); v.w = kred(v.w);
}

__device__ __forceinline__ float4 squash_vq(const float4& svU, float S) {
    const float invS = __frcp_rn(S);
    float4 s;
    s.x = svU.x * invS; s.y = svU.y * invS;
    s.z = svU.z * invS; s.w = svU.w * invS;
    float sq = dot4(s, s);
    sq = cred(sq);
    const float scale = __fsqrt_rn(sq) / (1.0f + sq);
    s.x *= scale; s.y *= scale; s.z *= scale; s.w *= scale;
    return s;
}

// One k-slab (16 k x 4 c x 4 n): load w[8], produce 4 n's prior quads, write
// LDS at Pl[nn*512 + g_local*64 + lane] (lane-consecutive, conflict-free).
__device__ __forceinline__ void do_j(const float4* __restrict__ T4,
                                     const float4* __restrict__ W4,
                                     float4* __restrict__ Pl,
                                     int o, int nbase, int k, int cg,
                                     int g_local, int lane) {
    float4 w[8];
    const float4* wp = W4 + (size_t)(o * 288 + k) * 32 + cg;
    #pragma unroll
    for (int i = 0; i < 8; ++i) w[i] = wp[i * 4];
    #pragma unroll
    for (int nn = 0; nn < 4; ++nn) {
        const float4* tp = T4 + (size_t)(nbase + nn) * 576 + k * 2;
        const float4 t0 = tp[0];
        const float4 t1 = tp[1];
        float4 a = make_float4(0.f, 0.f, 0.f, 0.f);
        fma4(a, t0.x, w[0]); fma4(a, t0.y, w[1]);
        fma4(a, t0.z, w[2]); fma4(a, t0.w, w[3]);
        fma4(a, t1.x, w[4]); fma4(a, t1.y, w[5]);
        fma4(a, t1.z, w[6]); fma4(a, t1.w, w[7]);
        Pl[nn * 512 + g_local * 64 + lane] = a;
    }
}

// ---------------------------------------------------------------------------
// caps_main: block = (o, 4 n's), 256 threads, wave = n in phase 2.
// Register diet vs R7: only slabs 0-9 are read back into registers (P[10],
// 40 regs); slabs 10-17 are computed into Pl LAST and STAY in LDS, read
// directly by phase 2 (3 passes x 8 conflict-free b128 reads). Per-wave regs
// ~94 peak -> __launch_bounds__(256,5) (empirical budget ~512/5=102, no
// spill) and LDS = 4*8*64 f4 = 32,768 B = exactly 5 blocks/CU: 20 waves/CU
// vs the 16 that pinned R0-R7 at 36% occupancy.
// Phase 2 is also pass-fused: one loop does d-dot -> lj -> exp -> S/svU per
// jj, so each P element is touched 3x (was 5x).
// Chunks: (8,2,8); crit path 5 do_j per wave (was 6).
// ---------------------------------------------------------------------------
__global__ __launch_bounds__(256, 5)
void caps_main(const float4* __restrict__ T4, const float4* __restrict__ W4,
               float* __restrict__ out) {
    __shared__ float4 Pl[4 * 8 * 64];   // 32,768 B -> 5 blocks/CU
    const int tid = threadIdx.x;
    const int o = blockIdx.y;
    const int nbase = blockIdx.x * 4;
    const int cg = tid & 3;
    const int wv = tid >> 6;            // [0,4)
    const int lane = tid & 63;
    const int kgp = lane >> 2;          // [0,16)

    float4 P[10];

    // ---- phase 1, chunk 0: slabs {wv, wv+4}, g_local = slab ----
    do_j(T4, W4, Pl, o, nbase, kgp + 16 * wv, cg, wv, lane);
    do_j(T4, W4, Pl, o, nbase, kgp + 16 * (wv + 4), cg, wv + 4, lane);
    __syncthreads();
    #pragma unroll
    for (int jj = 0; jj < 8; ++jj)
        P[jj] = Pl[wv * 512 + jj * 64 + lane];
    __syncthreads();

    // ---- phase 1, chunk 1: slabs 8,9 on waves 0,1 (g_local = slab-8) ----
    if (wv < 2)
        do_j(T4, W4, Pl, o, nbase, kgp + 16 * (8 + wv), cg, wv, lane);
    __syncthreads();
    P[8] = Pl[wv * 512 + lane];
    P[9] = Pl[wv * 512 + 64 + lane];
    __syncthreads();

    // ---- phase 1, chunk 2: slabs {10+wv, 14+wv} (g_local = slab-10),
    //      results stay in LDS for phase 2 ----
    do_j(T4, W4, Pl, o, nbase, kgp + 16 * (10 + wv), cg, wv, lane);
    __builtin_amdgcn_sched_barrier(0);  // don't overlap the two do_j's w[8]
    do_j(T4, W4, Pl, o, nbase, kgp + 16 * (14 + wv), cg, wv + 4, lane);
    __syncthreads();

    // ---- phase 2: dynamic routing, wave = n (= nbase + wv) ----
    const float4* Pw = Pl + wv * 512 + lane;   // + g*64 for slab 10+g

    // it 0: uniform probs
    float4 svU = make_float4(0.f, 0.f, 0.f, 0.f);
    #pragma unroll
    for (int jj = 0; jj < 10; ++jj) add4(svU, P[jj]);
    #pragma unroll
    for (int g = 0; g < 8; ++g) add4(svU, Pw[g * 64]);
    kred4(svU);
    float4 vq = squash_vq(svU, 288.0f);

    // pass 1: lj = <P,vq0>_c ; svU1 = sum exp(lj) * P ; S1 = sum exp(lj)
    float lj[18];
    float4 sv = make_float4(0.f, 0.f, 0.f, 0.f);
    float S = 0.f;
    #pragma unroll
    for (int jj = 0; jj < 10; ++jj) {
        float d = dot4(P[jj], vq);
        d = cred(d);
        lj[jj] = d;
        const float e = __expf(d);     // |lj| small; no max needed
        S += e;
        fma4(sv, e, P[jj]);
    }
    #pragma unroll
    for (int g = 0; g < 8; ++g) {
        const float4 q = Pw[g * 64];
        float d = dot4(q, vq);
        d = cred(d);
        lj[10 + g] = d;
        const float e = __expf(d);
        S += e;
        fma4(sv, e, q);
    }
    kred4(sv);
    S = kred(S);
    vq = squash_vq(sv, S);

    // pass 2: lj += <P,vq1>_c ; final svU/S ; squash
    sv = make_float4(0.f, 0.f, 0.f, 0.f);
    S = 0.f;
    #pragma unroll
    for (int jj = 0; jj < 10; ++jj) {
        float d = dot4(P[jj], vq);
        d = cred(d);
        const float e = __expf(lj[jj] + d);
        S += e;
        fma4(sv, e, P[jj]);
    }
    #pragma unroll
    for (int g = 0; g < 8; ++g) {
        const float4 q = Pw[g * 64];
        float d = dot4(q, vq);
        d = cred(d);
        const float e = __expf(lj[10 + g] + d);
        S += e;
        fma4(sv, e, q);
    }
    kred4(sv);
    S = kred(S);
    vq = squash_vq(sv, S);

    // ---- store: lanes kgp==0 write their c-quad ----
    if (kgp == 0) {
        const int n = nbase + wv;
        const int b = n / NSP;
        const int rm = n - b * NSP;
        float* op = out + (size_t)(b * 512 + o * 16 + cg * 4) * NSP + rm;
        op[0 * NSP] = vq.x;
        op[1 * NSP] = vq.y;
        op[2 * NSP] = vq.z;
        op[3 * NSP] = vq.w;
    }
}

extern "C" void kernel_launch(void* const* d_in, const int* in_sizes, int n_in,
                              void* d_out, int out_size, void* d_ws, size_t ws_size,
                              hipStream_t stream) {
    const float* x  = (const float*)d_in[0];   // (4, 256, 14, 14)
    const float* wt = (const float*)d_in[1];   // (32, 288, 8, 16)
    float* out = (float*)d_out;                // (4, 512, 12, 12)
    float4* T4 = (float4*)d_ws;                // 576*2304 floats = 5.3 MB

    build_T<<<dim3(576 * 576 / 256), 256, 0, stream>>>(x, T4);
    caps_main<<<dim3(144, 32), 256, 0, stream>>>(T4, (const float4*)wt, out);
}

// Round 10
// 123.703 us; speedup vs baseline: 1.0887x; 1.0887x over previous
//
#include <hip/hip_runtime.h>

static constexpr int OHW = 12, NSP = 144;

// ---------------------------------------------------------------------------
// build_T: gather x (4,256,14,14) -> T[n][k][i], n = b*144+oh*12+ow,
// k = (kh*3+kw)*32 + ic, i in [0,8). One float4 (4 consecutive i) per thread.
// (~4 us; fusing into caps_main regressed in R1.)
// ---------------------------------------------------------------------------
__global__ void build_T(const float* __restrict__ x, float4* __restrict__ T4) {
    const int g = blockIdx.x * 256 + threadIdx.x;   // [0, 576*576)
    const int n = g / 576;                          // 576 float4 per n
    const int q = g - n * 576;
    const int r = q << 2;                           // float offset in row
    const int k = r >> 3;
    const int i0 = r & 7;                           // 0 or 4
    const int ic = k & 31;
    const int kk = k >> 5;
    const int kh = kk / 3, kw = kk - kh * 3;
    const int b = n / NSP;
    const int rm = n - b * NSP;
    const int oh = rm / OHW, ow = rm - oh * OHW;
    const float* xp = x + (size_t)(b * 256 + ic * 8 + i0) * 196
                        + (oh + kh) * 14 + (ow + kw);
    float4 v;
    v.x = xp[0];
    v.y = xp[196];
    v.z = xp[392];
    v.w = xp[588];
    T4[g] = v;
}

__device__ __forceinline__ void fma4(float4& a, float s, const float4& w) {
    a.x = fmaf(s, w.x, a.x);
    a.y = fmaf(s, w.y, a.y);
    a.z = fmaf(s, w.z, a.z);
    a.w = fmaf(s, w.w, a.w);
}

__device__ __forceinline__ void add4(float4& a, const float4& b) {
    a.x += b.x; a.y += b.y; a.z += b.z; a.w += b.w;
}

__device__ __forceinline__ float dot4(const float4& a, const float4& b) {
    return a.x * b.x + a.y * b.y + a.z * b.z + a.w * b.w;
}

// ---- all-VALU reduce helpers ----------------------------------------------
// R7 (+4us): xor1/2 and row-rotate reduces -> DPP. This round: the two
// remaining LDS-pipe ops per kred (ds_swizzle xor16 + ds_bpermute xor32)
// -> v_permlane16_swap / v_permlane32_swap (gfx950 VALU). With old=src=v the
// returned pair {p[0],p[1]} sums to the group-exchange sum in every lane.
// NOTE R9: the builtins return a clang ext-vector; index with [0]/[1].
// __has_builtin guards: fallback = R7 behavior, not a failed build.
template <int CTRL>
__device__ __forceinline__ float dppmov(float v) {
    return __int_as_float(__builtin_amdgcn_update_dpp(
        0, __float_as_int(v), CTRL, 0xF, 0xF, true));
}

__device__ __forceinline__ float cred(float v) {       // sum over c-quad
    v += dppmov<0xB1>(v);   // quad_perm [1,0,3,2]
    v += dppmov<0x4E>(v);   // quad_perm [2,3,0,1]
    return v;
}

__device__ __forceinline__ float kred(float v) {       // sum over 16 kgp
    v += dppmov<0x124>(v);  // row_ror:4
    v += dppmov<0x128>(v);  // row_ror:8  -> stride-4 sum within 16-lane row
#if __has_builtin(__builtin_amdgcn_permlane16_swap)
    {   // row pair exchange
        auto p = __builtin_amdgcn_permlane16_swap(__float_as_int(v),
                                                  __float_as_int(v),
                                                  false, false);
        v = __int_as_float(p[0]) + __int_as_float(p[1]);
    }
#else
    v += __int_as_float(__builtin_amdgcn_ds_swizzle(__float_as_int(v), 0x401F));
#endif
#if __has_builtin(__builtin_amdgcn_permlane32_swap)
    {   // half exchange
        auto q = __builtin_amdgcn_permlane32_swap(__float_as_int(v),
                                                  __float_as_int(v),
                                                  false, false);
        v = __int_as_float(q[0]) + __int_as_float(q[1]);
    }
#else
    v += __shfl_xor(v, 32);
#endif
    return v;
}

__device__ __forceinline__ void kred4(float4& v) {
    v.x = kred(v.x); v.y = kred(v.y); v.z = kred(v.z); v.w = kred(v.w);
}

__device__ __forceinline__ float4 squash_vq(const float4& svU, float S) {
    const float invS = __frcp_rn(S);
    float4 s;
    s.x = svU.x * invS; s.y = svU.y * invS;
    s.z = svU.z * invS; s.w = svU.w * invS;
    float sq = dot4(s, s);
    sq = cred(sq);
    const float scale = __fsqrt_rn(sq) / (1.0f + sq);
    s.x *= scale; s.y *= scale; s.z *= scale; s.w *= scale;
    return s;
}

__device__ __forceinline__ void loadw(float4 w[8], const float4* __restrict__ W4,
                                      int o, int k, int cg) {
    const float4* wp = W4 + (size_t)(o * 288 + k) * 32 + cg;
    #pragma unroll
    for (int i = 0; i < 8; ++i) w[i] = wp[i * 4];
}

// One k-slab (16 k x 4 c x 4 n) with weights already in registers.
// LDS write address = const + lane (lane-consecutive, conflict-free b128).
__device__ __forceinline__ void compute_slab(const float4* __restrict__ T4,
                                             const float4 w[8],
                                             float4* __restrict__ Pl,
                                             int nbase, int k, int g_local,
                                             int lane) {
    #pragma unroll
    for (int nn = 0; nn < 4; ++nn) {
        const float4* tp = T4 + (size_t)(nbase + nn) * 576 + k * 2;
        const float4 t0 = tp[0];
        const float4 t1 = tp[1];
        float4 a = make_float4(0.f, 0.f, 0.f, 0.f);
        fma4(a, t0.x, w[0]); fma4(a, t0.y, w[1]);
        fma4(a, t0.z, w[2]); fma4(a, t0.w, w[3]);
        fma4(a, t1.x, w[4]); fma4(a, t1.y, w[5]);
        fma4(a, t1.z, w[6]); fma4(a, t1.w, w[7]);
        Pl[nn * 576 + g_local * 64 + lane] = a;
    }
}

// ---------------------------------------------------------------------------
// caps_main: R7 structure (best: 68.5 us). Block = (o, 4 n's), 256 threads,
// wave = n in phase 2, P[18] f4 per lane (64 VGPR + 64 AGPR = 128/wave ->
// 16 waves/CU; R2/R4/R5/R8 all proved cutting this state loses: any tighter
// launch-bound budget (512/arg total regs) spills P to scratch, khalf-split
// topology loses to barriers/imbalance, LDS-resident P loses to the spill at
// budget 102). __launch_bounds__(256,4) is the unique non-spilling point.
// Phase 1: R6 static slab schedule w/ double-buffered weights (neutral,
// kept). Phase 2: fused passes (d->lj->exp->S/sv in one sweep per jj) and
// 100% VALU-pipe reductions (DPP + permlane swaps; zero LDS-pipe ops).
// ---------------------------------------------------------------------------
__global__ __launch_bounds__(256, 4)
void caps_main(const float4* __restrict__ T4, const float4* __restrict__ W4,
               float* __restrict__ out) {
    __shared__ float4 Pl[4 * 9 * 64];   // 36,864 B
    const int tid = threadIdx.x;
    const int o = blockIdx.y;
    const int nbase = blockIdx.x * 4;
    const int cg = tid & 3;
    const int wv = tid >> 6;            // [0,4)
    const int lane = tid & 63;
    const int kgp = lane >> 2;          // [0,16)

    float4 P[18];
    float4 wA[8], wB[8];

    // ---- phase 1, chunk 0: slabs g in [0,9) ----
    loadw(wA, W4, o, kgp + 16 * wv, cg);
    loadw(wB, W4, o, kgp + 16 * (wv + 4), cg);
    if (wv == 0) {
        compute_slab(T4, wA, Pl, nbase, kgp, 0, lane);
        loadw(wA, W4, o, kgp + 16 * 8, cg);
        compute_slab(T4, wB, Pl, nbase, kgp + 16 * 4, 4, lane);
        compute_slab(T4, wA, Pl, nbase, kgp + 16 * 8, 8, lane);
    } else {
        compute_slab(T4, wA, Pl, nbase, kgp + 16 * wv, wv, lane);
        compute_slab(T4, wB, Pl, nbase, kgp + 16 * (wv + 4), wv + 4, lane);
    }
    __syncthreads();
    #pragma unroll
    for (int jj = 0; jj < 9; ++jj)
        P[jj] = Pl[wv * 576 + jj * 64 + lane];
    __syncthreads();

    // ---- phase 1, chunk 1: slabs g in [9,18), g_local = g - 9 ----
    const int h0 = (wv == 0) ? 12 : (8 + wv);   // wv: 12,9,10,11
    loadw(wA, W4, o, kgp + 16 * h0, cg);
    loadw(wB, W4, o, kgp + 16 * (h0 + 4), cg);
    if (wv == 1) {
        compute_slab(T4, wA, Pl, nbase, kgp + 16 * 9, 0, lane);
        loadw(wA, W4, o, kgp + 16 * 17, cg);
        compute_slab(T4, wB, Pl, nbase, kgp + 16 * 13, 4, lane);
        compute_slab(T4, wA, Pl, nbase, kgp + 16 * 17, 8, lane);
    } else {
        compute_slab(T4, wA, Pl, nbase, kgp + 16 * h0, h0 - 9, lane);
        compute_slab(T4, wB, Pl, nbase, kgp + 16 * (h0 + 4), h0 - 5, lane);
    }
    __syncthreads();
    #pragma unroll
    for (int jj = 9; jj < 18; ++jj)
        P[jj] = Pl[wv * 576 + (jj - 9) * 64 + lane];

    // ---- phase 2: dynamic routing, wave = n (= nbase + wv), fused passes --
    // it 0: uniform probs
    float4 sv = make_float4(0.f, 0.f, 0.f, 0.f);
    #pragma unroll
    for (int jj = 0; jj < 18; ++jj) add4(sv, P[jj]);
    kred4(sv);
    float4 vq = squash_vq(sv, 288.0f);

    // pass 1: lj = <P,vq0>_c ; sv = sum exp(lj)*P ; S = sum exp(lj)
    float lj[18];
    float S = 0.f;
    sv = make_float4(0.f, 0.f, 0.f, 0.f);
    #pragma unroll
    for (int jj = 0; jj < 18; ++jj) {
        float d = dot4(P[jj], vq);
        d = cred(d);
        lj[jj] = d;
        const float e = __expf(d);     // |lj| small; no max needed
        S += e;
        fma4(sv, e, P[jj]);
    }
    kred4(sv);
    S = kred(S);
    vq = squash_vq(sv, S);

    // pass 2: logits = lj + <P,vq1>_c ; final sv/S ; squash
    S = 0.f;
    sv = make_float4(0.f, 0.f, 0.f, 0.f);
    #pragma unroll
    for (int jj = 0; jj < 18; ++jj) {
        float d = dot4(P[jj], vq);
        d = cred(d);
        const float e = __expf(lj[jj] + d);
        S += e;
        fma4(sv, e, P[jj]);
    }
    kred4(sv);
    S = kred(S);
    vq = squash_vq(sv, S);

    // ---- store: lanes kgp==0 write their c-quad ----
    if (kgp == 0) {
        const int n = nbase + wv;
        const int b = n / NSP;
        const int rm = n - b * NSP;
        float* op = out + (size_t)(b * 512 + o * 16 + cg * 4) * NSP + rm;
        op[0 * NSP] = vq.x;
        op[1 * NSP] = vq.y;
        op[2 * NSP] = vq.z;
        op[3 * NSP] = vq.w;
    }
}

extern "C" void kernel_launch(void* const* d_in, const int* in_sizes, int n_in,
                              void* d_out, int out_size, void* d_ws, size_t ws_size,
                              hipStream_t stream) {
    const float* x  = (const float*)d_in[0];   // (4, 256, 14, 14)
    const float* wt = (const float*)d_in[1];   // (32, 288, 8, 16)
    float* out = (float*)d_out;                // (4, 512, 12, 12)
    float4* T4 = (float4*)d_ws;                // 576*2304 floats = 5.3 MB

    build_T<<<dim3(576 * 576 / 256), 256, 0, stream>>>(x, T4);
    caps_main<<<dim3(144, 32), 256, 0, stream>>>(T4, (const float4*)wt, out);
}

// Round 11
// 123.109 us; speedup vs baseline: 1.0939x; 1.0048x over previous
//
#include <hip/hip_runtime.h>

static constexpr int OHW = 12, NSP = 144;

// ---------------------------------------------------------------------------
// build_T: gather x (4,256,14,14) -> T[n][k][i], n = b*144+oh*12+ow,
// k = (kh*3+kw)*32 + ic, i in [0,8). One float4 (4 consecutive i) per thread.
// (~4 us; fusing into caps_main regressed in R1.)
// ---------------------------------------------------------------------------
__global__ void build_T(const float* __restrict__ x, float4* __restrict__ T4) {
    const int g = blockIdx.x * 256 + threadIdx.x;   // [0, 576*576)
    const int n = g / 576;                          // 576 float4 per n
    const int q = g - n * 576;
    const int r = q << 2;                           // float offset in row
    const int k = r >> 3;
    const int i0 = r & 7;                           // 0 or 4
    const int ic = k & 31;
    const int kk = k >> 5;
    const int kh = kk / 3, kw = kk - kh * 3;
    const int b = n / NSP;
    const int rm = n - b * NSP;
    const int oh = rm / OHW, ow = rm - oh * OHW;
    const float* xp = x + (size_t)(b * 256 + ic * 8 + i0) * 196
                        + (oh + kh) * 14 + (ow + kw);
    float4 v;
    v.x = xp[0];
    v.y = xp[196];
    v.z = xp[392];
    v.w = xp[588];
    T4[g] = v;
}

__device__ __forceinline__ void fma4(float4& a, float s, const float4& w) {
    a.x = fmaf(s, w.x, a.x);
    a.y = fmaf(s, w.y, a.y);
    a.z = fmaf(s, w.z, a.z);
    a.w = fmaf(s, w.w, a.w);
}

__device__ __forceinline__ void add4(float4& a, const float4& b) {
    a.x += b.x; a.y += b.y; a.z += b.z; a.w += b.w;
}

__device__ __forceinline__ float dot4(const float4& a, const float4& b) {
    return a.x * b.x + a.y * b.y + a.z * b.z + a.w * b.w;
}

// ---- all-VALU reduce helpers (R7 + R10) -----------------------------------
template <int CTRL>
__device__ __forceinline__ float dppmov(float v) {
    return __int_as_float(__builtin_amdgcn_update_dpp(
        0, __float_as_int(v), CTRL, 0xF, 0xF, true));
}

__device__ __forceinline__ float cred(float v) {       // sum over c-quad
    v += dppmov<0xB1>(v);   // quad_perm [1,0,3,2]
    v += dppmov<0x4E>(v);   // quad_perm [2,3,0,1]
    return v;
}

__device__ __forceinline__ float kred(float v) {       // sum over 16 kgp
    v += dppmov<0x124>(v);  // row_ror:4
    v += dppmov<0x128>(v);  // row_ror:8
#if __has_builtin(__builtin_amdgcn_permlane16_swap)
    {
        auto p = __builtin_amdgcn_permlane16_swap(__float_as_int(v),
                                                  __float_as_int(v),
                                                  false, false);
        v = __int_as_float(p[0]) + __int_as_float(p[1]);
    }
#else
    v += __int_as_float(__builtin_amdgcn_ds_swizzle(__float_as_int(v), 0x401F));
#endif
#if __has_builtin(__builtin_amdgcn_permlane32_swap)
    {
        auto q = __builtin_amdgcn_permlane32_swap(__float_as_int(v),
                                                  __float_as_int(v),
                                                  false, false);
        v = __int_as_float(q[0]) + __int_as_float(q[1]);
    }
#else
    v += __shfl_xor(v, 32);
#endif
    return v;
}

__device__ __forceinline__ void kred4(float4& v) {
    v.x = kred(v.x); v.y = kred(v.y); v.z = kred(v.z); v.w = kred(v.w);
}

__device__ __forceinline__ float4 squash_vq(const float4& svU, float S) {
    const float invS = __frcp_rn(S);
    float4 s;
    s.x = svU.x * invS; s.y = svU.y * invS;
    s.z = svU.z * invS; s.w = svU.w * invS;
    float sq = dot4(s, s);
    sq = cred(sq);
    const float scale = __fsqrt_rn(sq) / (1.0f + sq);
    s.x *= scale; s.y *= scale; s.z *= scale; s.w *= scale;
    return s;
}

// One k-slab (16 k x 4 c x 4 n): load w[8], produce 4 n's prior quads, write
// LDS at Pl[nn*512 + g_local*64 + lane] (lane-consecutive, conflict-free).
__device__ __forceinline__ void do_j(const float4* __restrict__ T4,
                                     const float4* __restrict__ W4,
                                     float4* __restrict__ Pl,
                                     int o, int nbase, int k, int cg,
                                     int g_local, int lane) {
    float4 w[8];
    const float4* wp = W4 + (size_t)(o * 288 + k) * 32 + cg;
    #pragma unroll
    for (int i = 0; i < 8; ++i) w[i] = wp[i * 4];
    #pragma unroll
    for (int nn = 0; nn < 4; ++nn) {
        const float4* tp = T4 + (size_t)(nbase + nn) * 576 + k * 2;
        const float4 t0 = tp[0];
        const float4 t1 = tp[1];
        float4 a = make_float4(0.f, 0.f, 0.f, 0.f);
        fma4(a, t0.x, w[0]); fma4(a, t0.y, w[1]);
        fma4(a, t0.z, w[2]); fma4(a, t0.w, w[3]);
        fma4(a, t1.x, w[4]); fma4(a, t1.y, w[5]);
        fma4(a, t1.z, w[6]); fma4(a, t1.w, w[7]);
        Pl[nn * 512 + g_local * 64 + lane] = a;
    }
}

// ---------------------------------------------------------------------------
// caps_main: R8 structure at the NON-SPILLING budget. Block = (o, 4 n's),
// 256 threads, wave = n in phase 2. Slabs 0-9 in registers (P[10], 40 f);
// slabs 10-17 computed LAST into Pl and STAY in LDS -- phase 2 reads them
// via the (phase-2-idle) LDS pipe instead of v_accvgpr moves. Evidence
// synthesis R0-R10: occupancy is capped by 128 unified regs/wave (64 VGPR +
// 64 AGPR holding P[18]); every P touch from AGPR is a VALU move (~290
// moves/wave across 3 passes). This structure cuts per-lane reg state
// 72->40 floats. R8's spill came from the (256,5)=102-reg budget (need
// ~122); here __launch_bounds__(256,4) keeps the 128 budget -> no spill,
// and most of P leaves AGPR. LDS = 4*8*64 f4 = 32,768 B.
// Chunks (8,2,8); crit path 5 do_j/wave. sched_barrier between chunk-2's
// do_j's stops w[8] double-buffering from pushing pressure past 128.
// Phase 2: fused passes (d->lj->exp->S/sv per jj), all-VALU reductions.
// ---------------------------------------------------------------------------
__global__ __launch_bounds__(256, 4)
void caps_main(const float4* __restrict__ T4, const float4* __restrict__ W4,
               float* __restrict__ out) {
    __shared__ float4 Pl[4 * 8 * 64];   // 32,768 B
    const int tid = threadIdx.x;
    const int o = blockIdx.y;
    const int nbase = blockIdx.x * 4;
    const int cg = tid & 3;
    const int wv = tid >> 6;            // [0,4)
    const int lane = tid & 63;
    const int kgp = lane >> 2;          // [0,16)

    float4 P[10];

    // ---- phase 1, chunk 0: slabs {wv, wv+4}, g_local = slab ----
    do_j(T4, W4, Pl, o, nbase, kgp + 16 * wv, cg, wv, lane);
    do_j(T4, W4, Pl, o, nbase, kgp + 16 * (wv + 4), cg, wv + 4, lane);
    __syncthreads();
    #pragma unroll
    for (int jj = 0; jj < 8; ++jj)
        P[jj] = Pl[wv * 512 + jj * 64 + lane];
    __syncthreads();

    // ---- phase 1, chunk 1: slabs 8,9 on waves 0,1 (g_local = slab-8) ----
    if (wv < 2)
        do_j(T4, W4, Pl, o, nbase, kgp + 16 * (8 + wv), cg, wv, lane);
    __syncthreads();
    P[8] = Pl[wv * 512 + lane];
    P[9] = Pl[wv * 512 + 64 + lane];
    __syncthreads();

    // ---- phase 1, chunk 2: slabs {10+wv, 14+wv} (g_local = slab-10),
    //      results stay in LDS for phase 2 ----
    do_j(T4, W4, Pl, o, nbase, kgp + 16 * (10 + wv), cg, wv, lane);
    __builtin_amdgcn_sched_barrier(0);  // don't overlap the two do_j's w[8]
    do_j(T4, W4, Pl, o, nbase, kgp + 16 * (14 + wv), cg, wv + 4, lane);
    __syncthreads();

    // ---- phase 2: dynamic routing, wave = n (= nbase + wv) ----
    const float4* Pw = Pl + wv * 512 + lane;   // + g*64 for slab 10+g

    // it 0: uniform probs
    float4 sv = make_float4(0.f, 0.f, 0.f, 0.f);
    #pragma unroll
    for (int jj = 0; jj < 10; ++jj) add4(sv, P[jj]);
    #pragma unroll
    for (int g = 0; g < 8; ++g) add4(sv, Pw[g * 64]);
    kred4(sv);
    float4 vq = squash_vq(sv, 288.0f);

    // pass 1: lj = <P,vq0>_c ; sv = sum exp(lj)*P ; S = sum exp(lj)
    float lj[18];
    float S = 0.f;
    sv = make_float4(0.f, 0.f, 0.f, 0.f);
    #pragma unroll
    for (int jj = 0; jj < 10; ++jj) {
        float d = dot4(P[jj], vq);
        d = cred(d);
        lj[jj] = d;
        const float e = __expf(d);     // |lj| small; no max needed
        S += e;
        fma4(sv, e, P[jj]);
    }
    #pragma unroll
    for (int g = 0; g < 8; ++g) {
        const float4 q = Pw[g * 64];
        float d = dot4(q, vq);
        d = cred(d);
        lj[10 + g] = d;
        const float e = __expf(d);
        S += e;
        fma4(sv, e, q);
    }
    kred4(sv);
    S = kred(S);
    vq = squash_vq(sv, S);

    // pass 2: logits = lj + <P,vq1>_c ; final sv/S ; squash
    S = 0.f;
    sv = make_float4(0.f, 0.f, 0.f, 0.f);
    #pragma unroll
    for (int jj = 0; jj < 10; ++jj) {
        float d = dot4(P[jj], vq);
        d = cred(d);
        const float e = __expf(lj[jj] + d);
        S += e;
        fma4(sv, e, P[jj]);
    }
    #pragma unroll
    for (int g = 0; g < 8; ++g) {
        const float4 q = Pw[g * 64];
        float d = dot4(q, vq);
        d = cred(d);
        const float e = __expf(lj[10 + g] + d);
        S += e;
        fma4(sv, e, q);
    }
    kred4(sv);
    S = kred(S);
    vq = squash_vq(sv, S);

    // ---- store: lanes kgp==0 write their c-quad ----
    if (kgp == 0) {
        const int n = nbase + wv;
        const int b = n / NSP;
        const int rm = n - b * NSP;
        float* op = out + (size_t)(b * 512 + o * 16 + cg * 4) * NSP + rm;
        op[0 * NSP] = vq.x;
        op[1 * NSP] = vq.y;
        op[2 * NSP] = vq.z;
        op[3 * NSP] = vq.w;
    }
}

extern "C" void kernel_launch(void* const* d_in, const int* in_sizes, int n_in,
                              void* d_out, int out_size, void* d_ws, size_t ws_size,
                              hipStream_t stream) {
    const float* x  = (const float*)d_in[0];   // (4, 256, 14, 14)
    const float* wt = (const float*)d_in[1];   // (32, 288, 8, 16)
    float* out = (float*)d_out;                // (4, 512, 12, 12)
    float4* T4 = (float4*)d_ws;                // 576*2304 floats = 5.3 MB

    build_T<<<dim3(576 * 576 / 256), 256, 0, stream>>>(x, T4);
    caps_main<<<dim3(144, 32), 256, 0, stream>>>(T4, (const float4*)wt, out);
}

// Round 12
// 119.517 us; speedup vs baseline: 1.1268x; 1.0301x over previous
//
#include <hip/hip_runtime.h>

static constexpr int OHW = 12, NSP = 144;

// ---------------------------------------------------------------------------
// build_T: gather x (4,256,14,14) -> T[n][k][i], n = b*144+oh*12+ow,
// k = (kh*3+kw)*32 + ic, i in [0,8). One float4 (4 consecutive i) per thread.
// ---------------------------------------------------------------------------
__global__ void build_T(const float* __restrict__ x, float4* __restrict__ T4) {
    const int g = blockIdx.x * 256 + threadIdx.x;   // [0, 576*576)
    const int n = g / 576;                          // 576 float4 per n
    const int q = g - n * 576;
    const int r = q << 2;                           // float offset in row
    const int k = r >> 3;
    const int i0 = r & 7;                           // 0 or 4
    const int ic = k & 31;
    const int kk = k >> 5;
    const int kh = kk / 3, kw = kk - kh * 3;
    const int b = n / NSP;
    const int rm = n - b * NSP;
    const int oh = rm / OHW, ow = rm - oh * OHW;
    const float* xp = x + (size_t)(b * 256 + ic * 8 + i0) * 196
                        + (oh + kh) * 14 + (ow + kw);
    float4 v;
    v.x = xp[0];
    v.y = xp[196];
    v.z = xp[392];
    v.w = xp[588];
    T4[g] = v;
}

__device__ __forceinline__ void fma4(float4& a, float s, const float4& w) {
    a.x = fmaf(s, w.x, a.x);
    a.y = fmaf(s, w.y, a.y);
    a.z = fmaf(s, w.z, a.z);
    a.w = fmaf(s, w.w, a.w);
}

__device__ __forceinline__ void add4(float4& a, const float4& b) {
    a.x += b.x; a.y += b.y; a.z += b.z; a.w += b.w;
}

__device__ __forceinline__ float dot4(const float4& a, const float4& b) {
    return a.x * b.x + a.y * b.y + a.z * b.z + a.w * b.w;
}

// ---- all-VALU reduce helpers (R7 + R10) -----------------------------------
template <int CTRL>
__device__ __forceinline__ float dppmov(float v) {
    return __int_as_float(__builtin_amdgcn_update_dpp(
        0, __float_as_int(v), CTRL, 0xF, 0xF, true));
}

__device__ __forceinline__ float cred(float v) {       // sum over c-quad
    v += dppmov<0xB1>(v);   // quad_perm [1,0,3,2]
    v += dppmov<0x4E>(v);   // quad_perm [2,3,0,1]
    return v;
}

__device__ __forceinline__ float kred(float v) {       // sum over 16 kgp
    v += dppmov<0x124>(v);  // row_ror:4
    v += dppmov<0x128>(v);  // row_ror:8
#if __has_builtin(__builtin_amdgcn_permlane16_swap)
    {
        auto p = __builtin_amdgcn_permlane16_swap(__float_as_int(v),
                                                  __float_as_int(v),
                                                  false, false);
        v = __int_as_float(p[0]) + __int_as_float(p[1]);
    }
#else
    v += __int_as_float(__builtin_amdgcn_ds_swizzle(__float_as_int(v), 0x401F));
#endif
#if __has_builtin(__builtin_amdgcn_permlane32_swap)
    {
        auto q = __builtin_amdgcn_permlane32_swap(__float_as_int(v),
                                                  __float_as_int(v),
                                                  false, false);
        v = __int_as_float(q[0]) + __int_as_float(q[1]);
    }
#else
    v += __shfl_xor(v, 32);
#endif
    return v;
}

__device__ __forceinline__ void kred4(float4& v) {
    v.x = kred(v.x); v.y = kred(v.y); v.z = kred(v.z); v.w = kred(v.w);
}

__device__ __forceinline__ float4 squash_vq(const float4& svU, float S) {
    const float invS = __frcp_rn(S);
    float4 s;
    s.x = svU.x * invS; s.y = svU.y * invS;
    s.z = svU.z * invS; s.w = svU.w * invS;
    float sq = dot4(s, s);
    sq = cred(sq);
    const float scale = __fsqrt_rn(sq) / (1.0f + sq);
    s.x *= scale; s.y *= scale; s.z *= scale; s.w *= scale;
    return s;
}

// One k-slab for EIGHT n's (16 k x 4 c x 8 n): load w[8] ONCE, 8x(2 T-loads +
// 32 FMA). Halves per-FMA weight traffic vs the 4-n variant (L2 W stream
// 677 -> 339 MB per dispatch). LDS write lane-consecutive, conflict-free.
__device__ __forceinline__ void do_j8(const float4* __restrict__ T4,
                                      const float4* __restrict__ W4,
                                      float4* __restrict__ Pl,
                                      int o, int nbase, int k, int cg,
                                      int g_local, int lane) {
    float4 w[8];
    const float4* wp = W4 + (size_t)(o * 288 + k) * 32 + cg;
    #pragma unroll
    for (int i = 0; i < 8; ++i) w[i] = wp[i * 4];
    #pragma unroll
    for (int nn = 0; nn < 8; ++nn) {
        const float4* tp = T4 + (size_t)(nbase + nn) * 576 + k * 2;
        const float4 t0 = tp[0];
        const float4 t1 = tp[1];
        float4 a = make_float4(0.f, 0.f, 0.f, 0.f);
        fma4(a, t0.x, w[0]); fma4(a, t0.y, w[1]);
        fma4(a, t0.z, w[2]); fma4(a, t0.w, w[3]);
        fma4(a, t1.x, w[4]); fma4(a, t1.y, w[5]);
        fma4(a, t1.z, w[6]); fma4(a, t1.w, w[7]);
        Pl[nn * 512 + g_local * 64 + lane] = a;
    }
}

// ---------------------------------------------------------------------------
// caps_main: block = (o, EIGHT n's), 512 threads = 8 waves, wave = n in
// phase 2 (phase 2 is the per-wave R10 code verbatim -- R4/R5 showed that
// splitting k across waves loses; splitting n across MORE waves does not).
// Rationale (R11 post-mortem): phase-1's L2 draw was ~24 TB/s (~70% of
// ceiling) from the 677 MB per-dispatch weight re-read; 8-n blocks halve it.
// Chunks smallest-first (2, 8, 8) keep peak liveness ~108 regs (P[10] +
// do_j8 working set) under the 128/wave budget of __launch_bounds__(512,4)
// (= the unique non-spilling budget established R2-R10). LDS = 8n x 8slab
// x 64 f4 = 65,536 B -> 2 blocks/CU = 16 waves/CU (unchanged occupancy).
// Grid 72x32 = 2304 blocks = 9/CU exactly.
// ---------------------------------------------------------------------------
__global__ __launch_bounds__(512, 4)
void caps_main(const float4* __restrict__ T4, const float4* __restrict__ W4,
               float* __restrict__ out) {
    __shared__ float4 Pl[8 * 8 * 64];   // 65,536 B
    const int tid = threadIdx.x;
    const int o = blockIdx.y;
    const int nbase = blockIdx.x * 8;
    const int cg = tid & 3;
    const int wv = tid >> 6;            // [0,8)
    const int lane = tid & 63;
    const int kgp = lane >> 2;          // [0,16)

    float4 P[18];

    // ---- phase 1, chunk 0: slabs 0,1 on waves 0,1 ----
    if (wv < 2)
        do_j8(T4, W4, Pl, o, nbase, kgp + 16 * wv, cg, wv, lane);
    __syncthreads();
    P[0] = Pl[wv * 512 + lane];
    P[1] = Pl[wv * 512 + 64 + lane];
    __syncthreads();

    // ---- phase 1, chunk 1: slabs 2..9, wave w -> slab 2+w ----
    do_j8(T4, W4, Pl, o, nbase, kgp + 16 * (2 + wv), cg, wv, lane);
    __syncthreads();
    #pragma unroll
    for (int j = 0; j < 8; ++j)
        P[2 + j] = Pl[wv * 512 + j * 64 + lane];
    __syncthreads();

    // ---- phase 1, chunk 2: slabs 10..17, wave w -> slab 10+w ----
    do_j8(T4, W4, Pl, o, nbase, kgp + 16 * (10 + wv), cg, wv, lane);
    __syncthreads();
    #pragma unroll
    for (int j = 0; j < 8; ++j)
        P[10 + j] = Pl[wv * 512 + j * 64 + lane];

    // ---- phase 2: dynamic routing, wave = n (= nbase + wv), fused passes --
    // it 0: uniform probs
    float4 sv = make_float4(0.f, 0.f, 0.f, 0.f);
    #pragma unroll
    for (int jj = 0; jj < 18; ++jj) add4(sv, P[jj]);
    kred4(sv);
    float4 vq = squash_vq(sv, 288.0f);

    // pass 1: lj = <P,vq0>_c ; sv = sum exp(lj)*P ; S = sum exp(lj)
    float lj[18];
    float S = 0.f;
    sv = make_float4(0.f, 0.f, 0.f, 0.f);
    #pragma unroll
    for (int jj = 0; jj < 18; ++jj) {
        float d = dot4(P[jj], vq);
        d = cred(d);
        lj[jj] = d;
        const float e = __expf(d);     // |lj| small; no max needed
        S += e;
        fma4(sv, e, P[jj]);
    }
    kred4(sv);
    S = kred(S);
    vq = squash_vq(sv, S);

    // pass 2: logits = lj + <P,vq1>_c ; final sv/S ; squash
    S = 0.f;
    sv = make_float4(0.f, 0.f, 0.f, 0.f);
    #pragma unroll
    for (int jj = 0; jj < 18; ++jj) {
        float d = dot4(P[jj], vq);
        d = cred(d);
        const float e = __expf(lj[jj] + d);
        S += e;
        fma4(sv, e, P[jj]);
    }
    kred4(sv);
    S = kred(S);
    vq = squash_vq(sv, S);

    // ---- store: lanes kgp==0 write their c-quad ----
    if (kgp == 0) {
        const int n = nbase + wv;
        const int b = n / NSP;
        const int rm = n - b * NSP;
        float* op = out + (size_t)(b * 512 + o * 16 + cg * 4) * NSP + rm;
        op[0 * NSP] = vq.x;
        op[1 * NSP] = vq.y;
        op[2 * NSP] = vq.z;
        op[3 * NSP] = vq.w;
    }
}

extern "C" void kernel_launch(void* const* d_in, const int* in_sizes, int n_in,
                              void* d_out, int out_size, void* d_ws, size_t ws_size,
                              hipStream_t stream) {
    const float* x  = (const float*)d_in[0];   // (4, 256, 14, 14)
    const float* wt = (const float*)d_in[1];   // (32, 288, 8, 16)
    float* out = (float*)d_out;                // (4, 512, 12, 12)
    float4* T4 = (float4*)d_ws;                // 576*2304 floats = 5.3 MB

    build_T<<<dim3(576 * 576 / 256), 256, 0, stream>>>(x, T4);
    caps_main<<<dim3(72, 32), 512, 0, stream>>>(T4, (const float4*)wt, out);
}